// Round 1
// baseline (741.751 us; speedup 1.0000x reference)
//
#include <hip/hip_runtime.h>
#include <hip/hip_bf16.h>

// GCN 2-layer: out = Ahat * relu(Ahat*(X W1)+b1) * W2 + b2
// Ahat = D^-1/2 (A+I) D^-1/2, N=100000, E=1600000, F 64->64->32.
// Strategy (round 1 baseline): fp32 throughout; atomic scatter-add aggregation.

#define N_FEAT_IN 64
#define N_FEAT_HID 64
#define N_FEAT_OUT 32

// ---- degree histogram: deg[dst] += 1 per edge ----
__global__ __launch_bounds__(256) void deg_hist(const int* __restrict__ dst,
                                                float* __restrict__ deg, int E) {
    int e = blockIdx.x * 256 + threadIdx.x;
    if (e < E) atomicAdd(&deg[dst[e]], 1.0f);
}

// ---- dinv[i] = rsqrt(deg[i] + 1)  (self-loop included) ----
__global__ __launch_bounds__(256) void finalize_dinv(float* __restrict__ deg, int n) {
    int i = blockIdx.x * 256 + threadIdx.x;
    if (i < n) deg[i] = rsqrtf(deg[i] + 1.0f);
}

// ---- GEMM: out[n,FO] = preop(A[n,64]) * W[64,FO] ----
// preop = relu(a + bias[k]) if RELU_BIAS else identity.
// 64 rows per block, 256 threads; A tile + W staged in LDS.
template <int FO, bool RELU_BIAS>
__global__ __launch_bounds__(256) void gemm_rows(const float* __restrict__ A,
                                                 const float* __restrict__ W,
                                                 const float* __restrict__ bias,
                                                 float* __restrict__ out, int n) {
    constexpr int K = 64;
    constexpr int CPT = FO / 4;  // cols per thread (16 or 8)
    __shared__ float As[64][K + 4];   // +4 pad keeps 16B alignment, breaks bank aliasing
    __shared__ float Ws[K][FO];

    const int t = threadIdx.x;
    const int r0 = blockIdx.x * 64;

    // stage W (K*FO floats) as float4
    constexpr int W4 = K * FO / 4;
    for (int i = t; i < W4; i += 256) {
        int k = i / (FO / 4);
        int c4 = (i % (FO / 4)) * 4;
        *(float4*)&Ws[k][c4] = *(const float4*)&W[k * FO + c4];
    }
    // stage A tile (64 rows x 64 cols) as float4, with optional relu(x+b1)
    for (int i = t; i < 1024; i += 256) {
        int row = i / 16;
        int c4 = (i % 16) * 4;
        int g = r0 + row;
        float4 v = make_float4(0.f, 0.f, 0.f, 0.f);
        if (g < n) {
            v = *(const float4*)&A[(size_t)g * K + c4];
            if (RELU_BIAS) {
                v.x = fmaxf(v.x + bias[c4 + 0], 0.f);
                v.y = fmaxf(v.y + bias[c4 + 1], 0.f);
                v.z = fmaxf(v.z + bias[c4 + 2], 0.f);
                v.w = fmaxf(v.w + bias[c4 + 3], 0.f);
            }
        }
        *(float4*)&As[row][c4] = v;
    }
    __syncthreads();

    const int row = t >> 2;
    const int c0 = (t & 3) * CPT;
    float acc[CPT];
#pragma unroll
    for (int j = 0; j < CPT; ++j) acc[j] = 0.f;

#pragma unroll
    for (int k = 0; k < K; ++k) {
        float xv = As[row][k];
#pragma unroll
        for (int j = 0; j < CPT; ++j) acc[j] = fmaf(xv, Ws[k][c0 + j], acc[j]);
    }

    int g = r0 + row;
    if (g < n) {
#pragma unroll
        for (int j4 = 0; j4 < CPT; j4 += 4) {
            float4 v = make_float4(acc[j4], acc[j4 + 1], acc[j4 + 2], acc[j4 + 3]);
            *(float4*)&out[(size_t)g * FO + c0 + j4] = v;
        }
    }
}

// ---- self-loop init: out[i,f] = dinv[i]^2 * feat[i,f] (+ bias[f]) ----
template <int F, bool ADD_BIAS>
__global__ __launch_bounds__(256) void selfloop_init(const float* __restrict__ dinv,
                                                     const float* __restrict__ feat,
                                                     const float* __restrict__ bias,
                                                     float* __restrict__ out, int n) {
    int tid = blockIdx.x * 256 + threadIdx.x;
    constexpr int SH = (F == 64) ? 6 : 5;
    int i = tid >> SH;
    int f = tid & (F - 1);
    if (i < n) {
        float di = dinv[i];
        float v = di * di * feat[tid];
        if (ADD_BIAS) v += bias[f];
        out[tid] = v;
    }
}

// ---- edge scatter: out[dst,f] += dinv[s]*dinv[d] * feat[src,f] ----
template <int F>
__global__ __launch_bounds__(256) void edge_scatter(const int* __restrict__ src,
                                                    const int* __restrict__ dst,
                                                    const float* __restrict__ dinv,
                                                    const float* __restrict__ feat,
                                                    float* __restrict__ out, int E) {
    int tid = blockIdx.x * 256 + threadIdx.x;
    constexpr int SH = (F == 64) ? 6 : 5;
    int e = tid >> SH;
    int f = tid & (F - 1);
    if (e < E) {
        int s = src[e];
        int d = dst[e];
        float w = dinv[s] * dinv[d];
        atomicAdd(&out[d * F + f], w * feat[s * F + f]);
    }
}

extern "C" void kernel_launch(void* const* d_in, const int* in_sizes, int n_in,
                              void* d_out, int out_size, void* d_ws, size_t ws_size,
                              hipStream_t stream) {
    const float* x  = (const float*)d_in[0];   // [n, 64]
    const int*   ei = (const int*)d_in[1];     // [2, E] (int32 per harness contract)
    const float* W1 = (const float*)d_in[2];   // [64, 64]
    const float* b1 = (const float*)d_in[3];   // [64]
    const float* W2 = (const float*)d_in[4];   // [64, 32]
    const float* b2 = (const float*)d_in[5];   // [32]
    float* out = (float*)d_out;                // [n, 32]

    const int n = in_sizes[0] / N_FEAT_IN;     // 100000
    const int E = in_sizes[1] / 2;             // 1600000
    const int* srcI = ei;
    const int* dstI = ei + E;

    // workspace layout
    char* ws = (char*)d_ws;
    size_t off = 0;
    float* dinv = (float*)(ws + off);
    off += (((size_t)n * 4) + 255) & ~(size_t)255;
    float* xw = (float*)(ws + off);            // [n,64] for layer1, reused as [n,32] for layer2
    off += (size_t)n * 64 * 4;
    float* agg1 = (float*)(ws + off);          // [n,64]

    // 1) degree -> dinv
    hipMemsetAsync(dinv, 0, (size_t)n * sizeof(float), stream);
    deg_hist<<<(E + 255) / 256, 256, 0, stream>>>(dstI, dinv, E);
    finalize_dinv<<<(n + 255) / 256, 256, 0, stream>>>(dinv, n);

    // 2) layer 1: xw1 = X*W1 ; agg1 = selfloop + scatter
    gemm_rows<64, false><<<(n + 63) / 64, 256, 0, stream>>>(x, W1, nullptr, xw, n);
    selfloop_init<64, false><<<((size_t)n * 64 + 255) / 256, 256, 0, stream>>>(dinv, xw, nullptr, agg1, n);
    edge_scatter<64><<<((size_t)E * 64 + 255) / 256, 256, 0, stream>>>(srcI, dstI, dinv, xw, agg1, E);

    // 3) layer 2: xw2 = relu(agg1+b1)*W2 ; out = selfloop + b2 + scatter
    gemm_rows<32, true><<<(n + 63) / 64, 256, 0, stream>>>(agg1, W2, b1, xw, n);
    selfloop_init<32, true><<<((size_t)n * 32 + 255) / 256, 256, 0, stream>>>(dinv, xw, b2, out, n);
    edge_scatter<32><<<((size_t)E * 32 + 255) / 256, 256, 0, stream>>>(srcI, dstI, dinv, xw, out, E);
}

// Round 2
// 428.798 us; speedup vs baseline: 1.7298x; 1.7298x over previous
//
#include <hip/hip_runtime.h>
#include <hip/hip_bf16.h>

// GCN 2-layer: out = Ahat * relu(Ahat*(X W1)+b1) * W2 + b2
// Round 2: replace atomic scatter with CSR pull-aggregation.
//   - counting-sort edges by dst (histogram + scan + cursor fill), built once
//   - dinv[src] folded into GEMM epilogue: xs = dinv .* (A W)
//   - agg[d] = dinv[d] * (sum_{s in N(d)} xs[s] + xs[d])   (self-loop = own row)

#define N_FEAT_IN 64

// ---- degree histogram (int) ----
__global__ __launch_bounds__(256) void deg_count(const int* __restrict__ dst,
                                                 int* __restrict__ cnt, int E) {
    int e = blockIdx.x * 256 + threadIdx.x;
    if (e < E) atomicAdd(&cnt[dst[e]], 1);
}

// ---- dinv[i] = rsqrt(deg[i] + 1)  (self-loop included) ----
__global__ __launch_bounds__(256) void finalize_dinv(const int* __restrict__ cnt,
                                                     float* __restrict__ dinv, int n) {
    int i = blockIdx.x * 256 + threadIdx.x;
    if (i < n) dinv[i] = rsqrtf((float)cnt[i] + 1.0f);
}

// ---- 3-phase exclusive scan over cnt[n] -> row_ptr[n+1] ----
__global__ __launch_bounds__(256) void scan_phase1(const int* __restrict__ cnt,
                                                   int* __restrict__ excl,
                                                   int* __restrict__ bsum, int n) {
    __shared__ int s[256];
    int t = threadIdx.x;
    int i = blockIdx.x * 256 + t;
    int v = (i < n) ? cnt[i] : 0;
    s[t] = v;
    __syncthreads();
    for (int off = 1; off < 256; off <<= 1) {
        int add = (t >= off) ? s[t - off] : 0;
        __syncthreads();
        s[t] += add;
        __syncthreads();
    }
    if (i < n) excl[i] = s[t] - v;            // block-local exclusive
    if (t == 255) bsum[blockIdx.x] = s[255];  // block total
}

__global__ __launch_bounds__(512) void scan_phase2(int* __restrict__ bsum, int nb) {
    __shared__ int s[512];
    int t = threadIdx.x;
    int v = (t < nb) ? bsum[t] : 0;
    s[t] = v;
    __syncthreads();
    for (int off = 1; off < 512; off <<= 1) {
        int add = (t >= off) ? s[t - off] : 0;
        __syncthreads();
        s[t] += add;
        __syncthreads();
    }
    if (t < nb) bsum[t] = s[t] - v;           // exclusive over block totals
}

__global__ __launch_bounds__(256) void scan_phase3(int* __restrict__ row_ptr,
                                                   const int* __restrict__ bsum,
                                                   int* __restrict__ cursor, int n, int E) {
    int i = blockIdx.x * 256 + threadIdx.x;
    if (i < n) {
        int v = row_ptr[i] + bsum[blockIdx.x];
        row_ptr[i] = v;
        cursor[i] = v;
    }
    if (i == 0) row_ptr[n] = E;
}

// ---- counting-sort fill: csr_src[pos] = src[e], grouped by dst ----
__global__ __launch_bounds__(256) void fill_csr(const int* __restrict__ src,
                                                const int* __restrict__ dst,
                                                int* __restrict__ cursor,
                                                int* __restrict__ csr_src, int E) {
    int e = blockIdx.x * 256 + threadIdx.x;
    if (e < E) {
        int pos = atomicAdd(&cursor[dst[e]], 1);
        csr_src[pos] = src[e];
    }
}

// ---- GEMM: out[n,FO] = dinv[row] * (preop(A[n,64]) * W[64,FO]) ----
// preop = relu(a + bias[k]) if RELU_BIAS else identity.
template <int FO, bool RELU_BIAS>
__global__ __launch_bounds__(256) void gemm_rows(const float* __restrict__ A,
                                                 const float* __restrict__ W,
                                                 const float* __restrict__ bias,
                                                 const float* __restrict__ dinv,
                                                 float* __restrict__ out, int n) {
    constexpr int K = 64;
    constexpr int CPT = FO / 4;
    __shared__ float As[64][K + 4];
    __shared__ float Ws[K][FO];

    const int t = threadIdx.x;
    const int r0 = blockIdx.x * 64;

    constexpr int W4 = K * FO / 4;
    for (int i = t; i < W4; i += 256) {
        int k = i / (FO / 4);
        int c4 = (i % (FO / 4)) * 4;
        *(float4*)&Ws[k][c4] = *(const float4*)&W[k * FO + c4];
    }
    for (int i = t; i < 1024; i += 256) {
        int row = i / 16;
        int c4 = (i % 16) * 4;
        int g = r0 + row;
        float4 v = make_float4(0.f, 0.f, 0.f, 0.f);
        if (g < n) {
            v = *(const float4*)&A[(size_t)g * K + c4];
            if (RELU_BIAS) {
                v.x = fmaxf(v.x + bias[c4 + 0], 0.f);
                v.y = fmaxf(v.y + bias[c4 + 1], 0.f);
                v.z = fmaxf(v.z + bias[c4 + 2], 0.f);
                v.w = fmaxf(v.w + bias[c4 + 3], 0.f);
            }
        }
        *(float4*)&As[row][c4] = v;
    }
    __syncthreads();

    const int row = t >> 2;
    const int c0 = (t & 3) * CPT;
    float acc[CPT];
#pragma unroll
    for (int j = 0; j < CPT; ++j) acc[j] = 0.f;

#pragma unroll
    for (int k = 0; k < K; ++k) {
        float xv = As[row][k];
#pragma unroll
        for (int j = 0; j < CPT; ++j) acc[j] = fmaf(xv, Ws[k][c0 + j], acc[j]);
    }

    int g = r0 + row;
    if (g < n) {
        float sc = dinv[g];
#pragma unroll
        for (int j4 = 0; j4 < CPT; j4 += 4) {
            float4 v = make_float4(acc[j4] * sc, acc[j4 + 1] * sc,
                                   acc[j4 + 2] * sc, acc[j4 + 3] * sc);
            *(float4*)&out[(size_t)g * FO + c0 + j4] = v;
        }
    }
}

// ---- pull aggregation: out[d,f] = dinv[d]*(sum_{s in N(d)} xs[s,f] + xs[d,f]) (+bias) ----
template <int F, bool ADD_BIAS>
__global__ __launch_bounds__(256) void aggregate(const int* __restrict__ row_ptr,
                                                 const int* __restrict__ csr_src,
                                                 const float* __restrict__ dinv,
                                                 const float* __restrict__ xs,
                                                 const float* __restrict__ bias,
                                                 float* __restrict__ out, int n) {
    constexpr int NPB = 256 / F;
    constexpr int SH = (F == 64) ? 6 : 5;
    int d = blockIdx.x * NPB + (threadIdx.x >> SH);
    int f = threadIdx.x & (F - 1);
    if (d >= n) return;

    int beg = row_ptr[d];
    int end = row_ptr[d + 1];
    float acc = xs[(size_t)d * F + f];  // self-loop term (already dinv[d]-scaled input row)
    int j = beg;
    for (; j + 4 <= end; j += 4) {
        int s0 = csr_src[j + 0];
        int s1 = csr_src[j + 1];
        int s2 = csr_src[j + 2];
        int s3 = csr_src[j + 3];
        float v0 = xs[(size_t)s0 * F + f];
        float v1 = xs[(size_t)s1 * F + f];
        float v2 = xs[(size_t)s2 * F + f];
        float v3 = xs[(size_t)s3 * F + f];
        acc += (v0 + v1) + (v2 + v3);
    }
    for (; j < end; ++j) acc += xs[(size_t)csr_src[j] * F + f];

    float r = dinv[d] * acc;
    if (ADD_BIAS) r += bias[f];
    out[(size_t)d * F + f] = r;
}

extern "C" void kernel_launch(void* const* d_in, const int* in_sizes, int n_in,
                              void* d_out, int out_size, void* d_ws, size_t ws_size,
                              hipStream_t stream) {
    const float* x  = (const float*)d_in[0];   // [n, 64]
    const int*   ei = (const int*)d_in[1];     // [2, E] (int32 per harness)
    const float* W1 = (const float*)d_in[2];   // [64, 64]
    const float* b1 = (const float*)d_in[3];   // [64]
    const float* W2 = (const float*)d_in[4];   // [64, 32]
    const float* b2 = (const float*)d_in[5];   // [32]
    float* out = (float*)d_out;                // [n, 32]

    const int n = in_sizes[0] / N_FEAT_IN;     // 100000
    const int E = in_sizes[1] / 2;             // 1600000
    const int* srcI = ei;
    const int* dstI = ei + E;

    const int NBLK = (n + 255) / 256;          // scan blocks (391)

    // workspace layout (aligned to 256B)
    char* ws = (char*)d_ws;
    size_t off = 0;
    auto alloc = [&](size_t bytes) {
        void* p = ws + off;
        off += (bytes + 255) & ~(size_t)255;
        return p;
    };
    int*   cnt     = (int*)alloc((size_t)n * 4);        // degree counts; reused as cursor
    float* dinv    = (float*)alloc((size_t)n * 4);
    int*   row_ptr = (int*)alloc((size_t)(n + 1) * 4);
    int*   bsum    = (int*)alloc((size_t)512 * 4);
    int*   csr_src = (int*)alloc((size_t)E * 4);
    float* xs      = (float*)alloc((size_t)n * 64 * 4); // layer1 GEMM out; reused [n,32] for layer2
    float* agg1    = (float*)alloc((size_t)n * 64 * 4);

    // 1) CSR build + dinv
    hipMemsetAsync(cnt, 0, (size_t)n * sizeof(int), stream);
    deg_count<<<(E + 255) / 256, 256, 0, stream>>>(dstI, cnt, E);
    finalize_dinv<<<NBLK, 256, 0, stream>>>(cnt, dinv, n);
    scan_phase1<<<NBLK, 256, 0, stream>>>(cnt, row_ptr, bsum, n);
    scan_phase2<<<1, 512, 0, stream>>>(bsum, NBLK);
    scan_phase3<<<NBLK, 256, 0, stream>>>(row_ptr, bsum, /*cursor=*/cnt, n, E);
    fill_csr<<<(E + 255) / 256, 256, 0, stream>>>(srcI, dstI, /*cursor=*/cnt, csr_src, E);

    // 2) layer 1: xs = dinv .* (X W1); agg1 = dinv .* (gather-sum + self)
    gemm_rows<64, false><<<(n + 63) / 64, 256, 0, stream>>>(x, W1, nullptr, dinv, xs, n);
    aggregate<64, false><<<(n + 3) / 4, 256, 0, stream>>>(row_ptr, csr_src, dinv, xs, nullptr, agg1, n);

    // 3) layer 2: xs2 = dinv .* (relu(agg1+b1) W2); out = dinv .* (gather-sum + self) + b2
    gemm_rows<32, true><<<(n + 63) / 64, 256, 0, stream>>>(agg1, W2, b1, dinv, xs, n);
    aggregate<32, true><<<(n + 7) / 8, 256, 0, stream>>>(row_ptr, csr_src, dinv, xs, b2, out, n);
}